// Round 7
// baseline (448.729 us; speedup 1.0000x reference)
//
#include <hip/hip_runtime.h>
#include <stdint.h>

// NeuralMemoryLinear on MI355X (gfx950). b=2, L=2048, dim=1024, n=8, dh=128.
// R7: revert R6's cross-scaling + swizzle (both regressed). k_fin rebuilt with
// 512-thread blocks: y-part 128x256 tiles (S staged once per 256 d-cols ->
// 11.4 B/MFLOP vs 15.2), wn-part 256x128. Barrier pairs per MFMA halved.
// k_qs restored as its own dispatch. Other kernels unchanged from R5/R6.

typedef __bf16 bf16x8 __attribute__((ext_vector_type(8)));
typedef float f32x4 __attribute__((ext_vector_type(4)));
typedef unsigned short u16;
typedef u16 u16x4 __attribute__((ext_vector_type(4)));

#define MFMA16 __builtin_amdgcn_mfma_f32_16x16x32_bf16

static __device__ __forceinline__ u16 f2b(float f) {
  union { float f; uint32_t u; } v; v.f = f;
  uint32_t r = v.u + 0x7FFFu + ((v.u >> 16) & 1u);
  return (u16)(r >> 16);
}
static __device__ __forceinline__ float b2f(u16 h) {
  union { uint32_t u; float f; } v; v.u = ((uint32_t)h) << 16;
  return v.f;
}

typedef __attribute__((address_space(1))) void gvoid_t;
typedef __attribute__((address_space(3))) void lvoid_t;
static __device__ __forceinline__ void gld16(const u16* g, u16* l) {
  __builtin_amdgcn_global_load_lds((gvoid_t*)(uintptr_t)g, (lvoid_t*)l, 16, 0, 0);
}

// ---- 256-thread staging (k_qkv / k_mid): 128x64 tile, two 128x32 halves ----
static __device__ __forceinline__ void stage64(u16* lds, const u16* __restrict__ g, int ld, int t) {
  const int r0 = t >> 2, c0 = (t & 3) << 3;
  const u16* ga = g + (size_t)r0 * ld + c0;
  const u16* gb = g + (size_t)(r0 + 64) * ld + c0;
  u16* la = lds + (r0 << 5) + c0;
  u16* lb = lds + ((r0 + 64) << 5) + c0;
  gld16(ga, la);
  gld16(gb, lb);
  gld16(ga + 32, la + 4096);
  gld16(gb + 32, lb + 4096);
}

// ---- 512-thread staging (k_fin): R x 64 tile, two R x 32 halves ----
// chunk i: row=i>>2, col=(i&3)*8; dest u16 = half*R*32 + i*8 (=> lane*16 B).
static __device__ __forceinline__ void stage128_T512(u16* lds, const u16* __restrict__ g,
                                                     int ld, int t) {
  const int r0 = t >> 2, c0 = (t & 3) << 3;
  const u16* ga = g + (size_t)r0 * ld + c0;
  gld16(ga, lds + t * 8);
  gld16(ga + 32, lds + 4096 + t * 8);
}
static __device__ __forceinline__ void stage256_T512(u16* lds, const u16* __restrict__ g,
                                                     int ld, int t) {
#pragma unroll
  for (int j = 0; j < 2; ++j) {
    const int i = j * 512 + t;
    const int r0 = i >> 2, c0 = (i & 3) << 3;
    const u16* ga = g + (size_t)r0 * ld + c0;
    gld16(ga, lds + i * 8);
    gld16(ga + 32, lds + 8192 + i * 8);
  }
}

#define TILE_IDS                                   \
  const int t = threadIdx.x;                       \
  const int w = t >> 6, ln = t & 63;               \
  const int wr = (w >> 1) << 6, wc = (w & 1) << 6; \
  const int q = ln >> 4, q8 = q << 3, r = ln & 15;

// BK=64 MFMA step; half-strides parameterized (A rows: astr u16, B rows: bstr).
static __device__ __forceinline__ void mfma64(const u16* As, const u16* Bs, int astr, int bstr,
                                              int wr, int wc, int q8, int r, f32x4 acc[4][4]) {
#pragma unroll
  for (int kk = 0; kk < 2; ++kk) {
    const u16* Ak = As + kk * astr;
    const u16* Bk = Bs + kk * bstr;
    bf16x8 af[4], bf[4];
#pragma unroll
    for (int s = 0; s < 4; ++s) af[s] = *(const bf16x8*)(Ak + ((wr + s * 16 + r) << 5) + q8);
#pragma unroll
    for (int s = 0; s < 4; ++s) bf[s] = *(const bf16x8*)(Bk + ((wc + s * 16 + r) << 5) + q8);
#pragma unroll
    for (int sm = 0; sm < 4; ++sm)
#pragma unroll
      for (int sn = 0; sn < 4; ++sn)
        acc[sm][sn] = MFMA16(af[sm], bf[sn], acc[sm][sn], 0, 0, 0);
  }
}
// acc element (sm, sn, i): A-row = wr+sm*16+q*4+i, B-row = wc+sn*16+r.

static __device__ __forceinline__ void gemm_loop(u16* As, u16* Bs,
    const u16* __restrict__ A, int lda, const u16* __restrict__ B, int ldb, int nc,
    int wr, int wc, int q8, int r, int t, f32x4 acc[4][4]) {
  for (int c = 0; c < nc; ++c) {
    __syncthreads();
    stage64(As, A + c * 64, lda, t);
    stage64(Bs, B + c * 64, ldb, t);
    __syncthreads();
    mfma64(As, Bs, 4096, 4096, wr, wc, q8, r, acc);
  }
}

// ---------------- D1: prep ----------------

__global__ __launch_bounds__(256) void k_prep(const float* __restrict__ x,
    const float* __restrict__ hidden, const float* __restrict__ wq,
    const float* __restrict__ wk, const float* __restrict__ wv,
    const float* __restrict__ wlr, const float* __restrict__ blr,
    const float* __restrict__ wwd, const float* __restrict__ bwd,
    const float* __restrict__ lbl, const float* __restrict__ lbw,
    u16* __restrict__ xb, u16* __restrict__ hb, u16* __restrict__ wqT,
    u16* __restrict__ wkT, u16* __restrict__ wvT,
    float* __restrict__ lr, float* __restrict__ lwd) {
  __shared__ float smem[4352];
  const int bid = blockIdx.x, t = threadIdx.x;
  if (bid < 4096) {
    const size_t i = ((size_t)bid * 256 + t) * 4;
    f32x4 v = *(const f32x4*)(x + i);
    u16x4 o;
#pragma unroll
    for (int j = 0; j < 4; ++j) o[j] = f2b(v[j]);
    *(u16x4*)(xb + i) = o;
  } else if (bid < 6144) {
    const size_t i = ((size_t)(bid - 4096) * 256 + t) * 4;
    f32x4 v = *(const f32x4*)(hidden + i);
    u16x4 o;
#pragma unroll
    for (int j = 0; j < 4; ++j) o[j] = f2b(v[j]);
    *(u16x4*)(hb + i) = o;
  } else if (bid < 9216) {
    const int idx = bid - 6144;
    const int z = idx >> 10, rem = idx & 1023;
    const float* src = z == 0 ? wq : z == 1 ? wk : wv;
    u16* dst = z == 0 ? wqT : z == 1 ? wkT : wvT;
    const int k0 = (rem >> 5) * 32, n0 = (rem & 31) * 32;
    float (*tile)[33] = (float(*)[33])smem;
    const int tx = t & 31, ty = t >> 5;
#pragma unroll
    for (int i = 0; i < 4; ++i)
      tile[ty + i * 8][tx] = src[(size_t)(k0 + ty + i * 8) * 1024 + n0 + tx];
    __syncthreads();
#pragma unroll
    for (int i = 0; i < 4; ++i)
      dst[(size_t)(n0 + ty + i * 8) * 1024 + k0 + tx] = f2b(tile[tx][ty + i * 8]);
  } else {
    const int row = bid - 9216;
    float pl[8] = {}, pw[8] = {};
    const float* xr = x + (size_t)row * 1024;
    for (int i = t; i < 1024; i += 256) {
      const float xv = xr[i];
      const float* wl = wlr + (size_t)i * 8;
      const float* ww = wwd + (size_t)i * 8;
#pragma unroll
      for (int j = 0; j < 8; ++j) { pl[j] += xv * wl[j]; pw[j] += xv * ww[j]; }
    }
    float (*red)[17] = (float(*)[17])smem;
#pragma unroll
    for (int j = 0; j < 8; ++j) { red[t][j] = pl[j]; red[t][j + 8] = pw[j]; }
    __syncthreads();
    for (int s = 128; s > 0; s >>= 1) {
      if (t < s) {
#pragma unroll
        for (int j = 0; j < 16; ++j) red[t][j] += red[t + s][j];
      }
      __syncthreads();
    }
    const int b = row >> 11, l = row & 2047;
    if (t < 8) {
      const float sig = 1.f / (1.f + expf(-(red[0][t] + blr[t])));
      lr[((size_t)b * 8 + t) * 2048 + l] = expf(lbl[t]) * sig;
    } else if (t < 16) {
      const int j = t - 8;
      const float sig = 1.f / (1.f + expf(-(red[0][t] + bwd[j])));
      lwd[((size_t)b * 8 + j) * 2048 + l] = log1pf(-expf(lbw[j]) * sig);
    }
  }
}

// ---------------- D2: scan ----------------

__global__ __launch_bounds__(256) void k_scan(const float* __restrict__ lwd,
                                              float* __restrict__ wdc, float* __restrict__ wdlast) {
  const int bn = blockIdx.x, t = threadIdx.x;
  const float* src = lwd + (size_t)bn * 2048;
  float v[8], s = 0.f;
#pragma unroll
  for (int i = 0; i < 8; ++i) { v[i] = src[t * 8 + i]; s += v[i]; }
  __shared__ float ps[256];
  ps[t] = s;
  __syncthreads();
  for (int off = 1; off < 256; off <<= 1) {
    const float add = (t >= off) ? ps[t - off] : 0.f;
    __syncthreads();
    ps[t] += add;
    __syncthreads();
  }
  float run = ps[t] - s;
  const float lwd_last = src[2047];
  float* wo = wdc + (size_t)bn * 2048;
  float* wl = wdlast + (size_t)bn * 2048;
#pragma unroll
  for (int i = 0; i < 8; ++i) {
    run += v[i];
    const int idx = t * 8 + i;
    wo[idx] = expf(run);
    const int c = (idx + 1 < 2047) ? (idx + 1) : 2047;
    wl[idx] = expf(lwd_last * (float)c);
  }
}

// ---------------- D3: qkv ----------------

__global__ __launch_bounds__(256) void k_qkv(const u16* __restrict__ xb,
    const u16* __restrict__ wqT, const u16* __restrict__ wkT, const u16* __restrict__ wvT,
    const float* __restrict__ bq, const float* __restrict__ bk, const float* __restrict__ bv,
    const float* __restrict__ wdl,
    u16* __restrict__ qb, u16* __restrict__ kb, u16* __restrict__ vT, u16* __restrict__ kTw) {
  __shared__ u16 As[8192], Bs[8192];
  TILE_IDS
  const int bid = blockIdx.x;
  f32x4 acc[4][4] = {};
  if (bid < 512) {
    const int z = bid >> 8, rem = bid & 255;
    const int m0 = (rem >> 3) * 128, n0 = (rem & 7) * 128;
    gemm_loop(As, Bs, xb + (size_t)m0 * 1024, 1024,
              (z ? wkT : wqT) + (size_t)n0 * 1024, 1024, 16, wr, wc, q8, r, t, acc);
    const float* bias = z ? bk : bq;
    u16* outp = z ? kb : qb;
#pragma unroll
    for (int sn = 0; sn < 4; ++sn) {
      const int col = n0 + wc + sn * 16 + r;
      const float bc = bias[col];
#pragma unroll
      for (int sm = 0; sm < 4; ++sm)
#pragma unroll
        for (int i = 0; i < 4; ++i) {
          const int gm = m0 + wr + sm * 16 + (q << 2) + i;
          outp[(size_t)gm * 1024 + col] = f2b(acc[sm][sn][i] + bc);
        }
    }
  } else {
    const int idx = bid - 512;
    const int zz = idx >> 7, rem = idx & 127;
    const int sel = zz >> 1, b = zz & 1;
    const int m0 = (rem >> 4) * 128, l0 = (rem & 15) * 128;
    gemm_loop(As, Bs, (sel ? wkT : wvT) + (size_t)m0 * 1024, 1024,
              xb + ((size_t)(b * 2048 + l0)) * 1024, 1024, 16, wr, wc, q8, r, t, acc);
#pragma unroll
    for (int sm = 0; sm < 4; ++sm)
#pragma unroll
      for (int i = 0; i < 4; ++i) {
        const int row = m0 + wr + sm * 16 + (q << 2) + i;
        const float bc = sel ? bk[row] : bv[row];
#pragma unroll
        for (int sn = 0; sn < 4; ++sn) {
          const int l = l0 + wc + sn * 16 + r;
          const float v = acc[sm][sn][i] + bc;
          if (!sel) {
            vT[((size_t)(b * 1024 + row)) * 2048 + l] = f2b(v);
          } else {
            const int n = row >> 7;
            kTw[((size_t)(b * 1024 + row)) * 2048 + l] =
                f2b(v * wdl[((size_t)(b * 8 + n)) * 2048 + l]);
          }
        }
      }
  }
}

// ---------------- D4: mid ----------------

__global__ __launch_bounds__(256) void k_mid(const u16* __restrict__ qb,
    const u16* __restrict__ kb, const u16* __restrict__ hb, const u16* __restrict__ vT,
    const float* __restrict__ lr, const float* __restrict__ lwd, const float* __restrict__ wdc,
    const float* __restrict__ hidden,
    u16* __restrict__ S, u16* __restrict__ AfT, float* __restrict__ y, float* __restrict__ out2) {
  __shared__ u16 As[8192], Bs[8192];
  TILE_IDS
  const int bid = blockIdx.x;
  if (bid < 2176) {
    const int p = bid % 136, bn = bid / 136, b = bn >> 3, n = bn & 7;
    int mi = (int)((sqrtf(8.f * p + 1.f) - 1.f) * 0.5f);
    while ((mi + 1) * (mi + 2) / 2 <= p) ++mi;
    while (mi * (mi + 1) / 2 > p) --mi;
    const int li = p - mi * (mi + 1) / 2;
    const int m0 = mi * 128, l0 = li * 128;
    f32x4 acc[4][4] = {};
    gemm_loop(As, Bs, qb + ((size_t)(b * 2048 + m0)) * 1024 + n * 128, 1024,
              kb + ((size_t)(b * 2048 + l0)) * 1024 + n * 128, 1024, 2, wr, wc, q8, r, t, acc);
    const float* lwdp = lwd + (size_t)bn * 2048;
    u16* Sp = S + (size_t)bn * 2048 * 2048;
#pragma unroll
    for (int sm = 0; sm < 4; ++sm)
#pragma unroll
      for (int i = 0; i < 4; ++i) {
        const int m = m0 + wr + sm * 16 + (q << 2) + i;
        const float lm = lwdp[m];
#pragma unroll
        for (int sn = 0; sn < 4; ++sn) {
          const int l = l0 + wc + sn * 16 + r;
          float v = 0.f;
          if (l <= m) {
            const float c = (l == m) ? (float)m : (float)(l + 1);
            v = -acc[sm][sn][i] * __expf(lm * c);
          }
          Sp[(size_t)m * 2048 + l] = f2b(v);
        }
      }
  } else if (bid < 4224) {
    const int idx = bid - 2176;
    const int bn = idx >> 7, rem = idx & 127;
    const int l0 = (rem >> 3) * 128, d0 = (rem & 7) * 128;
    const int b = bn >> 3, n = bn & 7;
    f32x4 acc[4][4] = {};
    gemm_loop(As, Bs, hb + ((size_t)(b * 1024 + d0)) * 1024 + n * 128, 1024,
              kb + ((size_t)(b * 2048 + l0)) * 1024 + n * 128, 1024, 2, wr, wc, q8, r, t, acc);
    const float* lrp = lr + (size_t)bn * 2048;
#pragma unroll
    for (int sm = 0; sm < 4; ++sm)
#pragma unroll
      for (int i = 0; i < 4; ++i) {
        const int d = d0 + wr + sm * 16 + (q << 2) + i;
#pragma unroll
        for (int sn = 0; sn < 4; ++sn) {
          const int l = l0 + wc + sn * 16 + r;
          const float v = (acc[sm][sn][i] - b2f(vT[((size_t)(b * 1024 + d)) * 2048 + l])) * lrp[l];
          AfT[((size_t)bn * 1024 + d) * 2048 + l] = f2b(v);
        }
      }
  } else if (bid < 5248) {
    const size_t i = ((size_t)(bid - 4224) * 256 + t) * 16;
#pragma unroll
    for (int j = 0; j < 4; ++j)
      *(f32x4*)(y + i + j * 4) = f32x4{0.f, 0.f, 0.f, 0.f};
  } else {
    const size_t i = ((size_t)(bid - 5248) * 256 + t) * 4;
    const int b = (int)(i >> 20);
    const int hd = (int)(i & 1023);
    const float wdcl = wdc[((size_t)(b * 8 + (hd >> 7))) * 2048 + 2047];
    f32x4 v = *(const f32x4*)(hidden + i);
    v *= wdcl;
    *(f32x4*)(out2 + i) = v;
  }
}

// ---------------- D5: qs (in-place qb *= wdc) ----------------

__global__ __launch_bounds__(256) void k_qs(u16* __restrict__ qb, const float* __restrict__ wdc) {
  const size_t base = ((size_t)blockIdx.x * 256 + threadIdx.x) * 4;
  const int b = (int)(base >> 21);
  const int rem = (int)(base & 2097151);
  const int m = rem >> 10, hd = rem & 1023;
  const float sc = wdc[((size_t)b * 8 + (hd >> 7)) * 2048 + m];
  u16x4 v = *(const u16x4*)(qb + base);
#pragma unroll
  for (int j = 0; j < 4; ++j) v[j] = f2b(b2f(v[j]) * sc);
  *(u16x4*)(qb + base) = v;
}

// ---------------- D6: fin (512 threads; y 128x256, wn 256x128) ----------------

__global__ __launch_bounds__(512) void k_fin(const u16* __restrict__ S,
    const u16* __restrict__ AfT, const u16* __restrict__ Qs, const u16* __restrict__ hb,
    const u16* __restrict__ kTw, float* __restrict__ y, float* __restrict__ out2) {
  __shared__ u16 buf[24576];  // 48 KB
  const int t = threadIdx.x;
  const int w = t >> 6, ln = t & 63;
  const int q = ln >> 4, q8 = q << 3, r = ln & 15;
  const int bid = blockIdx.x;
  if (bid < 512) {
    // y partials: 128 m x 256 d per block; waves 2(m) x 4(d).
    u16* As = buf;           // S tile   128x64 (16 KB)
    u16* Bs = buf + 8192;    // AfT tile 256x64 (32 KB)
    const int z = bid >> 5, mip = (bid >> 2) & 7, dj = bid & 3;
    const int b = z >> 3, n = z & 7;
    const int d0 = dj * 256;
    const int wr = (w >> 2) << 6, wc = (w & 3) << 6;
    float* Y = y + (size_t)b * 2048 * 1024;
#pragma unroll 1
    for (int tsel = 0; tsel < 2; ++tsel) {
      const int mi = tsel ? (15 - mip) : mip;
      const int m0 = mi * 128;
      f32x4 acc[4][4] = {};
      const u16* A = S + (size_t)z * 2048 * 2048 + (size_t)m0 * 2048;
      const u16* B = AfT + ((size_t)z * 1024 + d0) * 2048;
      const int nc = 2 * mi + 2;
      for (int c = 0; c < nc; ++c) {
        __syncthreads();
        stage128_T512(As, A + c * 64, 2048, t);
        stage256_T512(Bs, B + c * 64, 2048, t);
        __syncthreads();
        mfma64(As, Bs, 4096, 8192, wr, wc, q8, r, acc);
      }
      const u16* A2 = Qs + ((size_t)(b * 2048 + m0)) * 1024 + n * 128;
      const u16* B2 = hb + ((size_t)(b * 1024 + d0)) * 1024 + n * 128;
      for (int c = 0; c < 2; ++c) {
        __syncthreads();
        stage128_T512(As, A2 + c * 64, 1024, t);
        stage256_T512(Bs, B2 + c * 64, 1024, t);
        __syncthreads();
        mfma64(As, Bs, 4096, 8192, wr, wc, q8, r, acc);
      }
#pragma unroll
      for (int sm = 0; sm < 4; ++sm)
#pragma unroll
        for (int i = 0; i < 4; ++i) {
          const int m = m0 + wr + sm * 16 + (q << 2) + i;
#pragma unroll
          for (int sn = 0; sn < 4; ++sn)
            atomicAdd(&Y[(size_t)m * 1024 + d0 + wc + sn * 16 + r], acc[sm][sn][i]);
        }
    }
  } else {
    // W_next partials: 256 d x 128 hd per block; waves 4(d) x 2(hd); K 2-way.
    u16* As = buf;           // AfT tile 256x64 (32 KB)
    u16* Bs = buf + 16384;   // kTw tile 128x64 (16 KB)
    const int idx = bid - 512;  // di(4) nj(8) b(2) kc(2)
    const int di = idx >> 5, nj = (idx >> 2) & 7, b = (idx >> 1) & 1, kc = idx & 1;
    const int d0 = di * 256;
    const int bn = b * 8 + nj;
    const int wr = (w >> 1) << 6, wc = (w & 1) << 6;
    f32x4 acc[4][4] = {};
    const u16* A = AfT + ((size_t)bn * 1024 + d0) * 2048 + kc * 1024;
    const u16* B = kTw + ((size_t)(b * 1024 + nj * 128)) * 2048 + kc * 1024;
    for (int c = 0; c < 16; ++c) {
      __syncthreads();
      stage256_T512(As, A + c * 64, 2048, t);
      stage128_T512(Bs, B + c * 64, 2048, t);
      __syncthreads();
      mfma64(As, Bs, 8192, 4096, wr, wc, q8, r, acc);
    }
#pragma unroll
    for (int sm = 0; sm < 4; ++sm)
#pragma unroll
      for (int i = 0; i < 4; ++i) {
        const int d = d0 + wr + sm * 16 + (q << 2) + i;
#pragma unroll
        for (int sn = 0; sn < 4; ++sn) {
          const int hd = nj * 128 + wc + sn * 16 + r;
          atomicAdd(&out2[((size_t)(b * 1024 + d)) * 1024 + hd], -acc[sm][sn][i]);
        }
      }
  }
}

// ---------------- launch ----------------

extern "C" void kernel_launch(void* const* d_in, const int* in_sizes, int n_in,
                              void* d_out, int out_size, void* d_ws, size_t ws_size,
                              hipStream_t stream) {
  const float* x      = (const float*)d_in[0];
  const float* hidden = (const float*)d_in[1];
  const float* lbl    = (const float*)d_in[2];
  const float* wlr    = (const float*)d_in[3];
  const float* blr    = (const float*)d_in[4];
  const float* lbw    = (const float*)d_in[5];
  const float* wwd    = (const float*)d_in[6];
  const float* bwd    = (const float*)d_in[7];
  const float* wq     = (const float*)d_in[8];
  const float* bq     = (const float*)d_in[9];
  const float* wk     = (const float*)d_in[10];
  const float* bk     = (const float*)d_in[11];
  const float* wv     = (const float*)d_in[12];
  const float* bv     = (const float*)d_in[13];
  float* out = (float*)d_out;

  // Manual layout, 228.5 MB. xb/w*T die before k_mid writes S -> overlap with S.
  char* ws = (char*)d_ws;
  const size_t MB = 1u << 20;
  u16* S     = (u16*)(ws);                 // [0,128MB)   k_mid -> k_fin
  u16* xb    = (u16*)(ws);                 // [0,8MB)     dead after k_qkv
  u16* wqT   = (u16*)(ws + 8 * MB);
  u16* wkT   = (u16*)(ws + 10 * MB);
  u16* wvT   = (u16*)(ws + 12 * MB);
  u16* AfT   = (u16*)(ws + 128 * MB);      // [128,192)
  u16* hb    = (u16*)(ws + 192 * MB);      // [192,196)
  u16* qb    = (u16*)(ws + 196 * MB);      // [196,204)   becomes Qs after k_qs
  u16* kb    = (u16*)(ws + 204 * MB);      // [204,212)
  u16* kTw   = (u16*)(ws + 212 * MB);      // [212,220)
  u16* vT    = (u16*)(ws + 220 * MB);      // [220,228)
  float* lr  = (float*)(ws + 228 * MB);
  float* lwd = (float*)(ws + 228 * MB + 131072);
  float* wdc = (float*)(ws + 228 * MB + 262144);
  float* wdl = (float*)(ws + 228 * MB + 393216);   // ends at 228.5 MB
  (void)ws_size; (void)n_in; (void)in_sizes; (void)out_size;

  const size_t YSZ = (size_t)2 * 2048 * 1024;

  k_prep<<<13312, 256, 0, stream>>>(x, hidden, wq, wk, wv, wlr, blr, wwd, bwd,
                                    lbl, lbw, xb, hb, wqT, wkT, wvT, lr, lwd);
  k_scan<<<16, 256, 0, stream>>>(lwd, wdc, wdl);
  k_qkv<<<1024, 256, 0, stream>>>(xb, wqT, wkT, wvT, bq, bk, bv, wdl, qb, kb, vT, kTw);
  k_mid<<<7296, 256, 0, stream>>>(qb, kb, hb, vT, lr, lwd, wdc, hidden, S, AfT, out, out + YSZ);
  k_qs<<<4096, 256, 0, stream>>>(qb, wdc);
  k_fin<<<640, 512, 0, stream>>>(S, AfT, qb, hb, kTw, out, out + YSZ);
}

// Round 9
// 427.607 us; speedup vs baseline: 1.0494x; 1.0494x over previous
//
#include <hip/hip_runtime.h>
#include <stdint.h>

// NeuralMemoryLinear on MI355X (gfx950). b=2, L=2048, dim=1024, n=8, dh=128.
// R9 (= R8 with the mfma_tile64 call-site fix): k_fin is the best-measured R5
// config (256 thr, 128x128, BK=64) + y-part XCD swizzle only. k_qs eliminated:
// k_qkv writes q pre-scaled by exp(cum[m]) (Qs), k_mid's S epilogue
// compensates in log space (exp(lm*c - cum[m])). k_scan stores raw cumsum.
// 5 dispatches: prep / scan / qkv / mid / fin.

typedef __bf16 bf16x8 __attribute__((ext_vector_type(8)));
typedef float f32x4 __attribute__((ext_vector_type(4)));
typedef unsigned short u16;
typedef u16 u16x4 __attribute__((ext_vector_type(4)));

#define MFMA16 __builtin_amdgcn_mfma_f32_16x16x32_bf16

static __device__ __forceinline__ u16 f2b(float f) {
  union { float f; uint32_t u; } v; v.f = f;
  uint32_t r = v.u + 0x7FFFu + ((v.u >> 16) & 1u);
  return (u16)(r >> 16);
}
static __device__ __forceinline__ float b2f(u16 h) {
  union { uint32_t u; float f; } v; v.u = ((uint32_t)h) << 16;
  return v.f;
}

typedef __attribute__((address_space(1))) void gvoid_t;
typedef __attribute__((address_space(3))) void lvoid_t;
static __device__ __forceinline__ void gld16(const u16* g, u16* l) {
  __builtin_amdgcn_global_load_lds((gvoid_t*)(uintptr_t)g, (lvoid_t*)l, 16, 0, 0);
}

// Stage a 128x64 tile as two 128x32 halves; half h at lds + h*4096 (u16),
// each half in the conflict-free [128][32] layout (lds dest = t*16 B).
static __device__ __forceinline__ void stage64(u16* lds, const u16* __restrict__ g, int ld, int t) {
  const int r0 = t >> 2, c0 = (t & 3) << 3;
  const u16* ga = g + (size_t)r0 * ld + c0;
  const u16* gb = g + (size_t)(r0 + 64) * ld + c0;
  u16* la = lds + (r0 << 5) + c0;
  u16* lb = lds + ((r0 + 64) << 5) + c0;
  gld16(ga, la);
  gld16(gb, lb);
  gld16(ga + 32, la + 4096);
  gld16(gb + 32, lb + 4096);
}

#define TILE_IDS                                   \
  const int t = threadIdx.x;                       \
  const int w = t >> 6, ln = t & 63;               \
  const int wr = (w >> 1) << 6, wc = (w & 1) << 6; \
  const int q = ln >> 4, q8 = q << 3, r = ln & 15;

static __device__ __forceinline__ void mfma_tile64(const u16* As, const u16* Bs,
                                                   int wr, int wc, int q8, int r, f32x4 acc[4][4]) {
#pragma unroll
  for (int kk = 0; kk < 2; ++kk) {
    const u16* Ak = As + (kk << 12);
    const u16* Bk = Bs + (kk << 12);
    bf16x8 af[4], bf[4];
#pragma unroll
    for (int s = 0; s < 4; ++s) af[s] = *(const bf16x8*)(Ak + ((wr + s * 16 + r) << 5) + q8);
#pragma unroll
    for (int s = 0; s < 4; ++s) bf[s] = *(const bf16x8*)(Bk + ((wc + s * 16 + r) << 5) + q8);
#pragma unroll
    for (int sm = 0; sm < 4; ++sm)
#pragma unroll
      for (int sn = 0; sn < 4; ++sn)
        acc[sm][sn] = MFMA16(af[sm], bf[sn], acc[sm][sn], 0, 0, 0);
  }
}
// acc element (sm, sn, i): A-row = wr+sm*16+q*4+i, B-row = wc+sn*16+r.

static __device__ __forceinline__ void gemm_loop(u16* As, u16* Bs,
    const u16* __restrict__ A, int lda, const u16* __restrict__ B, int ldb, int nc,
    int wr, int wc, int q8, int r, int t, f32x4 acc[4][4]) {
  for (int c = 0; c < nc; ++c) {
    __syncthreads();
    stage64(As, A + c * 64, lda, t);
    stage64(Bs, B + c * 64, ldb, t);
    __syncthreads();
    mfma_tile64(As, Bs, wr, wc, q8, r, acc);
  }
}

// ---------------- D1: prep ----------------

__global__ __launch_bounds__(256) void k_prep(const float* __restrict__ x,
    const float* __restrict__ hidden, const float* __restrict__ wq,
    const float* __restrict__ wk, const float* __restrict__ wv,
    const float* __restrict__ wlr, const float* __restrict__ blr,
    const float* __restrict__ wwd, const float* __restrict__ bwd,
    const float* __restrict__ lbl, const float* __restrict__ lbw,
    u16* __restrict__ xb, u16* __restrict__ hb, u16* __restrict__ wqT,
    u16* __restrict__ wkT, u16* __restrict__ wvT,
    float* __restrict__ lr, float* __restrict__ lwd) {
  __shared__ float smem[4352];
  const int bid = blockIdx.x, t = threadIdx.x;
  if (bid < 4096) {
    const size_t i = ((size_t)bid * 256 + t) * 4;
    f32x4 v = *(const f32x4*)(x + i);
    u16x4 o;
#pragma unroll
    for (int j = 0; j < 4; ++j) o[j] = f2b(v[j]);
    *(u16x4*)(xb + i) = o;
  } else if (bid < 6144) {
    const size_t i = ((size_t)(bid - 4096) * 256 + t) * 4;
    f32x4 v = *(const f32x4*)(hidden + i);
    u16x4 o;
#pragma unroll
    for (int j = 0; j < 4; ++j) o[j] = f2b(v[j]);
    *(u16x4*)(hb + i) = o;
  } else if (bid < 9216) {
    const int idx = bid - 6144;
    const int z = idx >> 10, rem = idx & 1023;
    const float* src = z == 0 ? wq : z == 1 ? wk : wv;
    u16* dst = z == 0 ? wqT : z == 1 ? wkT : wvT;
    const int k0 = (rem >> 5) * 32, n0 = (rem & 31) * 32;
    float (*tile)[33] = (float(*)[33])smem;
    const int tx = t & 31, ty = t >> 5;
#pragma unroll
    for (int i = 0; i < 4; ++i)
      tile[ty + i * 8][tx] = src[(size_t)(k0 + ty + i * 8) * 1024 + n0 + tx];
    __syncthreads();
#pragma unroll
    for (int i = 0; i < 4; ++i)
      dst[(size_t)(n0 + ty + i * 8) * 1024 + k0 + tx] = f2b(tile[tx][ty + i * 8]);
  } else {
    const int row = bid - 9216;
    float pl[8] = {}, pw[8] = {};
    const float* xr = x + (size_t)row * 1024;
    for (int i = t; i < 1024; i += 256) {
      const float xv = xr[i];
      const float* wl = wlr + (size_t)i * 8;
      const float* ww = wwd + (size_t)i * 8;
#pragma unroll
      for (int j = 0; j < 8; ++j) { pl[j] += xv * wl[j]; pw[j] += xv * ww[j]; }
    }
    float (*red)[17] = (float(*)[17])smem;
#pragma unroll
    for (int j = 0; j < 8; ++j) { red[t][j] = pl[j]; red[t][j + 8] = pw[j]; }
    __syncthreads();
    for (int s = 128; s > 0; s >>= 1) {
      if (t < s) {
#pragma unroll
        for (int j = 0; j < 16; ++j) red[t][j] += red[t + s][j];
      }
      __syncthreads();
    }
    const int b = row >> 11, l = row & 2047;
    if (t < 8) {
      const float sig = 1.f / (1.f + expf(-(red[0][t] + blr[t])));
      lr[((size_t)b * 8 + t) * 2048 + l] = expf(lbl[t]) * sig;
    } else if (t < 16) {
      const int j = t - 8;
      const float sig = 1.f / (1.f + expf(-(red[0][t] + bwd[j])));
      lwd[((size_t)b * 8 + j) * 2048 + l] = log1pf(-expf(lbw[j]) * sig);
    }
  }
}

// ---------------- D2: scan (stores RAW cumsum, not exp) ----------------

__global__ __launch_bounds__(256) void k_scan(const float* __restrict__ lwd,
                                              float* __restrict__ cum, float* __restrict__ wdlast) {
  const int bn = blockIdx.x, t = threadIdx.x;
  const float* src = lwd + (size_t)bn * 2048;
  float v[8], s = 0.f;
#pragma unroll
  for (int i = 0; i < 8; ++i) { v[i] = src[t * 8 + i]; s += v[i]; }
  __shared__ float ps[256];
  ps[t] = s;
  __syncthreads();
  for (int off = 1; off < 256; off <<= 1) {
    const float add = (t >= off) ? ps[t - off] : 0.f;
    __syncthreads();
    ps[t] += add;
    __syncthreads();
  }
  float run = ps[t] - s;
  const float lwd_last = src[2047];
  float* co = cum + (size_t)bn * 2048;
  float* wl = wdlast + (size_t)bn * 2048;
#pragma unroll
  for (int i = 0; i < 8; ++i) {
    run += v[i];
    const int idx = t * 8 + i;
    co[idx] = run;
    const int c = (idx + 1 < 2047) ? (idx + 1) : 2047;
    wl[idx] = expf(lwd_last * (float)c);
  }
}

// ---------------- D3: qkv (q written PRE-SCALED by exp(cum[m]) = Qs) --------

__global__ __launch_bounds__(256) void k_qkv(const u16* __restrict__ xb,
    const u16* __restrict__ wqT, const u16* __restrict__ wkT, const u16* __restrict__ wvT,
    const float* __restrict__ bq, const float* __restrict__ bk, const float* __restrict__ bv,
    const float* __restrict__ wdl, const float* __restrict__ cum,
    u16* __restrict__ qb, u16* __restrict__ kb, u16* __restrict__ vT, u16* __restrict__ kTw) {
  __shared__ u16 As[8192], Bs[8192];
  TILE_IDS
  const int bid = blockIdx.x;
  f32x4 acc[4][4] = {};
  if (bid < 512) {
    const int z = bid >> 8, rem = bid & 255;
    const int m0 = (rem >> 3) * 128, n0 = (rem & 7) * 128;
    gemm_loop(As, Bs, xb + (size_t)m0 * 1024, 1024,
              (z ? wkT : wqT) + (size_t)n0 * 1024, 1024, 16, wr, wc, q8, r, t, acc);
    const float* bias = z ? bk : bq;
    u16* outp = z ? kb : qb;
#pragma unroll
    for (int sn = 0; sn < 4; ++sn) {
      const int col = n0 + wc + sn * 16 + r;
      const float bc = bias[col];
      const int n = col >> 7;
#pragma unroll
      for (int sm = 0; sm < 4; ++sm)
#pragma unroll
        for (int i = 0; i < 4; ++i) {
          const int gm = m0 + wr + sm * 16 + (q << 2) + i;
          float v = acc[sm][sn][i] + bc;
          if (z == 0) {  // q: scale by exp(cum[b,n,m]) -> Qs
            const int b = gm >> 11, m = gm & 2047;
            v *= __expf(cum[((size_t)(b * 8 + n)) * 2048 + m]);
          }
          outp[(size_t)gm * 1024 + col] = f2b(v);
        }
    }
  } else {
    const int idx = bid - 512;
    const int zz = idx >> 7, rem = idx & 127;
    const int sel = zz >> 1, b = zz & 1;
    const int m0 = (rem >> 4) * 128, l0 = (rem & 15) * 128;
    gemm_loop(As, Bs, (sel ? wkT : wvT) + (size_t)m0 * 1024, 1024,
              xb + ((size_t)(b * 2048 + l0)) * 1024, 1024, 16, wr, wc, q8, r, t, acc);
#pragma unroll
    for (int sm = 0; sm < 4; ++sm)
#pragma unroll
      for (int i = 0; i < 4; ++i) {
        const int row = m0 + wr + sm * 16 + (q << 2) + i;
        const float bc = sel ? bk[row] : bv[row];
#pragma unroll
        for (int sn = 0; sn < 4; ++sn) {
          const int l = l0 + wc + sn * 16 + r;
          const float v = acc[sm][sn][i] + bc;
          if (!sel) {
            vT[((size_t)(b * 1024 + row)) * 2048 + l] = f2b(v);
          } else {
            const int n = row >> 7;
            kTw[((size_t)(b * 1024 + row)) * 2048 + l] =
                f2b(v * wdl[((size_t)(b * 8 + n)) * 2048 + l]);
          }
        }
      }
  }
}

// ---------------- D4: mid (S with log-space compensation) -------------------

__global__ __launch_bounds__(256) void k_mid(const u16* __restrict__ qb,
    const u16* __restrict__ kb, const u16* __restrict__ hb, const u16* __restrict__ vT,
    const float* __restrict__ lr, const float* __restrict__ lwd, const float* __restrict__ cum,
    const float* __restrict__ hidden,
    u16* __restrict__ S, u16* __restrict__ AfT, float* __restrict__ y, float* __restrict__ out2) {
  __shared__ u16 As[8192], Bs[8192];
  TILE_IDS
  const int bid = blockIdx.x;
  if (bid < 2176) {
    const int p = bid % 136, bn = bid / 136, b = bn >> 3, n = bn & 7;
    int mi = (int)((sqrtf(8.f * p + 1.f) - 1.f) * 0.5f);
    while ((mi + 1) * (mi + 2) / 2 <= p) ++mi;
    while (mi * (mi + 1) / 2 > p) --mi;
    const int li = p - mi * (mi + 1) / 2;
    const int m0 = mi * 128, l0 = li * 128;
    f32x4 acc[4][4] = {};
    gemm_loop(As, Bs, qb + ((size_t)(b * 2048 + m0)) * 1024 + n * 128, 1024,
              kb + ((size_t)(b * 2048 + l0)) * 1024 + n * 128, 1024, 2, wr, wc, q8, r, t, acc);
    const float* lwdp = lwd + (size_t)bn * 2048;
    const float* cump = cum + (size_t)bn * 2048;
    u16* Sp = S + (size_t)bn * 2048 * 2048;
#pragma unroll
    for (int sm = 0; sm < 4; ++sm)
#pragma unroll
      for (int i = 0; i < 4; ++i) {
        const int m = m0 + wr + sm * 16 + (q << 2) + i;
        const float lm = lwdp[m];
        const float cm = cump[m];
#pragma unroll
        for (int sn = 0; sn < 4; ++sn) {
          const int l = l0 + wc + sn * 16 + r;
          float v = 0.f;
          if (l <= m) {
            const float c = (l == m) ? (float)m : (float)(l + 1);
            v = -acc[sm][sn][i] * __expf(lm * c - cm);  // A was q*exp(cm)
          }
          Sp[(size_t)m * 2048 + l] = f2b(v);
        }
      }
  } else if (bid < 4224) {
    const int idx = bid - 2176;
    const int bn = idx >> 7, rem = idx & 127;
    const int l0 = (rem >> 3) * 128, d0 = (rem & 7) * 128;
    const int b = bn >> 3, n = bn & 7;
    f32x4 acc[4][4] = {};
    gemm_loop(As, Bs, hb + ((size_t)(b * 1024 + d0)) * 1024 + n * 128, 1024,
              kb + ((size_t)(b * 2048 + l0)) * 1024 + n * 128, 1024, 2, wr, wc, q8, r, t, acc);
    const float* lrp = lr + (size_t)bn * 2048;
#pragma unroll
    for (int sm = 0; sm < 4; ++sm)
#pragma unroll
      for (int i = 0; i < 4; ++i) {
        const int d = d0 + wr + sm * 16 + (q << 2) + i;
#pragma unroll
        for (int sn = 0; sn < 4; ++sn) {
          const int l = l0 + wc + sn * 16 + r;
          const float v = (acc[sm][sn][i] - b2f(vT[((size_t)(b * 1024 + d)) * 2048 + l])) * lrp[l];
          AfT[((size_t)bn * 1024 + d) * 2048 + l] = f2b(v);
        }
      }
  } else if (bid < 5248) {
    const size_t i = ((size_t)(bid - 4224) * 256 + t) * 16;
#pragma unroll
    for (int j = 0; j < 4; ++j)
      *(f32x4*)(y + i + j * 4) = f32x4{0.f, 0.f, 0.f, 0.f};
  } else {
    const size_t i = ((size_t)(bid - 5248) * 256 + t) * 4;
    const int b = (int)(i >> 20);
    const int hd = (int)(i & 1023);
    const float wdcl = __expf(cum[((size_t)(b * 8 + (hd >> 7))) * 2048 + 2047]);
    f32x4 v = *(const f32x4*)(hidden + i);
    v *= wdcl;
    *(f32x4*)(out2 + i) = v;
  }
}

// ---------------- D5: fin (R5 core + y-part XCD swizzle) ----------------

__global__ __launch_bounds__(256) void k_fin(const u16* __restrict__ S,
    const u16* __restrict__ AfT, const u16* __restrict__ Qs, const u16* __restrict__ hb,
    const u16* __restrict__ kTw, float* __restrict__ y, float* __restrict__ out2) {
  __shared__ u16 As[8192], Bs[8192];
  TILE_IDS
  const int bid = blockIdx.x;
  if (bid < 1024) {
    // Swizzle: the 8 dj blocks of one (z,mip) group sit at bids spaced 8 apart
    // (same XCD under round-robin) and adjacent in launch order.
    const int window = bid >> 6, within = bid & 63;
    const int dj = within >> 3, low = within & 7;
    const int g = window * 8 + low;
    const int z = g >> 3, mip = g & 7;
    const int b = z >> 3, n = z & 7;
    const int d0 = dj * 128;
    float* Y = y + (size_t)b * 2048 * 1024;
#pragma unroll 1
    for (int tsel = 0; tsel < 2; ++tsel) {
      const int mi = tsel ? (15 - mip) : mip;
      const int m0 = mi * 128;
      f32x4 acc[4][4] = {};
      gemm_loop(As, Bs, S + (size_t)z * 2048 * 2048 + (size_t)m0 * 2048, 2048,
                AfT + ((size_t)z * 1024 + d0) * 2048, 2048, 2 * mi + 2, wr, wc, q8, r, t, acc);
      gemm_loop(As, Bs, Qs + ((size_t)(b * 2048 + m0)) * 1024 + n * 128, 1024,
                hb + ((size_t)(b * 1024 + d0)) * 1024 + n * 128, 1024, 2, wr, wc, q8, r, t, acc);
#pragma unroll
      for (int sm = 0; sm < 4; ++sm)
#pragma unroll
        for (int i = 0; i < 4; ++i) {
          const int m = m0 + wr + sm * 16 + (q << 2) + i;
#pragma unroll
          for (int sn = 0; sn < 4; ++sn)
            atomicAdd(&Y[(size_t)m * 1024 + d0 + wc + sn * 16 + r], acc[sm][sn][i]);
        }
    }
  } else {
    const int idx = bid - 1024;
    const int z = idx >> 6, rem = idx & 63;
    const int d0 = (rem >> 3) * 128, nj = rem & 7;
    const int b = z >> 2, kc = z & 3;
    const int bn = b * 8 + nj;
    f32x4 acc[4][4] = {};
    gemm_loop(As, Bs, AfT + ((size_t)bn * 1024 + d0) * 2048 + kc * 512, 2048,
              kTw + ((size_t)(b * 1024 + nj * 128)) * 2048 + kc * 512, 2048, 8,
              wr, wc, q8, r, t, acc);
#pragma unroll
    for (int sm = 0; sm < 4; ++sm)
#pragma unroll
      for (int i = 0; i < 4; ++i) {
        const int d = d0 + wr + sm * 16 + (q << 2) + i;
#pragma unroll
        for (int sn = 0; sn < 4; ++sn) {
          const int hd = nj * 128 + wc + sn * 16 + r;
          atomicAdd(&out2[((size_t)(b * 1024 + d)) * 1024 + hd], -acc[sm][sn][i]);
        }
      }
  }
}

// ---------------- launch ----------------

extern "C" void kernel_launch(void* const* d_in, const int* in_sizes, int n_in,
                              void* d_out, int out_size, void* d_ws, size_t ws_size,
                              hipStream_t stream) {
  const float* x      = (const float*)d_in[0];
  const float* hidden = (const float*)d_in[1];
  const float* lbl    = (const float*)d_in[2];
  const float* wlr    = (const float*)d_in[3];
  const float* blr    = (const float*)d_in[4];
  const float* lbw    = (const float*)d_in[5];
  const float* wwd    = (const float*)d_in[6];
  const float* bwd    = (const float*)d_in[7];
  const float* wq     = (const float*)d_in[8];
  const float* bq     = (const float*)d_in[9];
  const float* wk     = (const float*)d_in[10];
  const float* bk     = (const float*)d_in[11];
  const float* wv     = (const float*)d_in[12];
  const float* bv     = (const float*)d_in[13];
  float* out = (float*)d_out;

  // Manual layout, 228.5 MB. xb/w*T die before k_mid writes S -> overlap with S.
  char* ws = (char*)d_ws;
  const size_t MB = 1u << 20;
  u16* S     = (u16*)(ws);                 // [0,128MB)   k_mid -> k_fin
  u16* xb    = (u16*)(ws);                 // [0,8MB)     dead after k_qkv
  u16* wqT   = (u16*)(ws + 8 * MB);
  u16* wkT   = (u16*)(ws + 10 * MB);
  u16* wvT   = (u16*)(ws + 12 * MB);
  u16* AfT   = (u16*)(ws + 128 * MB);      // [128,192)
  u16* hb    = (u16*)(ws + 192 * MB);      // [192,196)
  u16* qb    = (u16*)(ws + 196 * MB);      // [196,204)   = Qs (pre-scaled)
  u16* kb    = (u16*)(ws + 204 * MB);      // [204,212)
  u16* kTw   = (u16*)(ws + 212 * MB);      // [212,220)
  u16* vT    = (u16*)(ws + 220 * MB);      // [220,228)
  float* lr  = (float*)(ws + 228 * MB);
  float* lwd = (float*)(ws + 228 * MB + 131072);
  float* cum = (float*)(ws + 228 * MB + 262144);   // raw cumsum(lwd)
  float* wdl = (float*)(ws + 228 * MB + 393216);   // ends at 228.5 MB
  (void)ws_size; (void)n_in; (void)in_sizes; (void)out_size;

  const size_t YSZ = (size_t)2 * 2048 * 1024;

  k_prep<<<13312, 256, 0, stream>>>(x, hidden, wq, wk, wv, wlr, blr, wwd, bwd,
                                    lbl, lbw, xb, hb, wqT, wkT, wvT, lr, lwd);
  k_scan<<<16, 256, 0, stream>>>(lwd, cum, wdl);
  k_qkv<<<1024, 256, 0, stream>>>(xb, wqT, wkT, wvT, bq, bk, bv, wdl, cum, qb, kb, vT, kTw);
  k_mid<<<7296, 256, 0, stream>>>(qb, kb, hb, vT, lr, lwd, cum, hidden, S, AfT, out, out + YSZ);
  k_fin<<<1536, 256, 0, stream>>>(S, AfT, qb, hb, kTw, out, out + YSZ);
}